// Round 5
// baseline (890.408 us; speedup 1.0000x reference)
//
#include <hip/hip_runtime.h>
#include <hip/hip_bf16.h>
#include <cstdint>

#define NV 20000
#define NE 40000
#define NODE_IN 74
#define EDGE_IN 12
#define D 64
#define EHID 128
#define NSTEPS 6

typedef __bf16 bf16x8 __attribute__((ext_vector_type(8)));
typedef float f32x4 __attribute__((ext_vector_type(4)));

// ---------------- node projection: h = relu(nf @ Wp^T + bp); also zero neigh ----------------
__global__ __launch_bounds__(256) void k_proj(const float* __restrict__ nf,
                                              const float* __restrict__ W,
                                              const float* __restrict__ b,
                                              float* __restrict__ h,
                                              float* __restrict__ neigh) {
  __shared__ float sn[4][NODE_IN];
  int tid = threadIdx.x;
  int nb = blockIdx.x * 4;
  for (int idx = tid; idx < 4 * NODE_IN; idx += 256) {
    int r = idx / NODE_IN, c = idx % NODE_IN;
    sn[r][c] = nf[(size_t)(nb + r) * NODE_IN + c];
  }
  __syncthreads();
  int nl = tid >> 6, o = tid & 63;
  float acc = b[o];
#pragma unroll
  for (int i = 0; i < NODE_IN; ++i) acc = fmaf(sn[nl][i], W[o * NODE_IN + i], acc);
  h[(size_t)(nb + nl) * D + o] = fmaxf(acc, 0.f);
  neigh[(size_t)(nb + nl) * D + o] = 0.f;
}

// ------------- edge net layer 1: t = relu(ef @ W1^T + b1), bf16 -------------
__global__ __launch_bounds__(256) void k_edge1(const float* __restrict__ ef,
                                               const float* __restrict__ W1,
                                               const float* __restrict__ b1,
                                               __hip_bfloat16* __restrict__ t_bf) {
  __shared__ float se[2][EDGE_IN];
  int tid = threadIdx.x;
  int eb = blockIdx.x * 2;
  if (tid < 2 * EDGE_IN)
    se[tid / EDGE_IN][tid % EDGE_IN] =
        ef[(size_t)(eb + tid / EDGE_IN) * EDGE_IN + tid % EDGE_IN];
  __syncthreads();
  int el = tid >> 7, k = tid & 127;
  float acc = b1[k];
#pragma unroll
  for (int j = 0; j < EDGE_IN; ++j) acc = fmaf(se[el][j], W1[k * EDGE_IN + j], acc);
  t_bf[(size_t)(eb + el) * EHID + k] = __float2bfloat16(fmaxf(acc, 0.f));
}

// ---------------- W2 fp32 -> bf16 ----------------
__global__ __launch_bounds__(256) void k_cvt_w2(const float* __restrict__ W2,
                                                __hip_bfloat16* __restrict__ w2b) {
  int idx = blockIdx.x * 256 + threadIdx.x;
  if (idx < D * D * EHID) w2b[idx] = __float2bfloat16(W2[idx]);
}

// ------- build GRU B matrix (256 x 128), hi/lo bf16 split -------
__global__ __launch_bounds__(256) void k_build_b(const float* __restrict__ Wih,
                                                 const float* __restrict__ Whh,
                                                 __hip_bfloat16* __restrict__ Bhi,
                                                 __hip_bfloat16* __restrict__ Blo) {
  int idx = blockIdx.x * 256 + threadIdx.x;  // 32768 total
  int n = idx >> 7, k = idx & 127;
  int o = n & 63, cls = n >> 6;
  float v;
  if (cls == 0)      v = (k < 64) ? Wih[o * 64 + k]         : Whh[o * 64 + (k - 64)];
  else if (cls == 1) v = (k < 64) ? Wih[(64 + o) * 64 + k]  : Whh[(64 + o) * 64 + (k - 64)];
  else if (cls == 2) v = (k < 64) ? Wih[(128 + o) * 64 + k] : 0.f;
  else               v = (k < 64) ? 0.f                     : Whh[(128 + o) * 64 + (k - 64)];
  __hip_bfloat16 hi = __float2bfloat16(v);
  Bhi[idx] = hi;
  Blo[idx] = __float2bfloat16(v - __bfloat162float(hi));
}

// ------- fused NNConv message+aggregate -------
// Grid: (NE/64)*2 blocks. Block (eblk, iblk) handles 64 edges, i in [iblk*32, iblk*32+32).
// Wave w computes output cols [w*16, w*16+16) for all 64 edges.
// m_e[o] = sum_i h[src_e][i] * (b2[i*64+o] + t_e @ W2[i*64+o]^T); atomics sum i-halves.
// W2 B-frags: 4-deep prefetch in INDIVIDUALLY NAMED vector regs (macro-expanded,
// compile-time only — runtime-indexed buffers spilled to scratch in R3).
#define HS_STRIDE 68
__global__ __launch_bounds__(256) void k_msg(const float* __restrict__ h,
                                             const __hip_bfloat16* __restrict__ t_bf,
                                             const __hip_bfloat16* __restrict__ w2,
                                             const float* __restrict__ b2,
                                             const int* __restrict__ src,
                                             const int* __restrict__ dst,
                                             float* __restrict__ neigh) {
  __shared__ __align__(16) float HsT[32 * HS_STRIDE];  // [i_local][edge] fp32, 8.7 KB
  __shared__ int Ss[64];
  __shared__ int Ds[64];
  int tid = threadIdx.x;
  int eblk = blockIdx.x >> 1, iblk = blockIdx.x & 1;
  int e0 = eblk * 64;      // NE % 64 == 0
  int ig0 = iblk * 32;     // global i base for this block

  if (tid < 64) {
    Ss[tid] = src[e0 + tid];
    Ds[tid] = dst[e0 + tid];
  }
  __syncthreads();
  // gather h[src][ig0..ig0+32) -> HsT[i][r]
  for (int idx = tid; idx < 64 * 32; idx += 256) {
    int r = idx >> 5, i = idx & 31;
    HsT[i * HS_STRIDE + r] = h[(size_t)Ss[r] * D + ig0 + i];
  }

  int wave = tid >> 6, lane = tid & 63;
  int lr = lane & 15, lq = lane >> 4;

  // loop-invariant A-frags: t rows for 4 M-tiles x 4 k-steps (direct from global)
  bf16x8 tf[4][4];
#pragma unroll
  for (int mt = 0; mt < 4; ++mt)
#pragma unroll
    for (int ks = 0; ks < 4; ++ks)
      tf[mt][ks] = *(const bf16x8*)(t_bf + (size_t)(e0 + mt * 16 + lr) * EHID + ks * 32 + lq * 8);

  const int ocol = wave * 16 + lr;
  const __hip_bfloat16* wbase = w2 + (size_t)ocol * EHID + lq * 8;

  bf16x8 ba0, ba1, ba2, ba3, bb0, bb1, bb2, bb3;
  bf16x8 bc0, bc1, bc2, bc3, bd0, bd1, bd2, bd3;
  float b2a, b2b, b2c, b2d;

#define LDW2(BUF, B2V, IG) do {                                          \
    const __hip_bfloat16* wp_ = wbase + (size_t)(IG) * (64 * EHID);      \
    BUF##0 = *(const bf16x8*)(wp_);                                      \
    BUF##1 = *(const bf16x8*)(wp_ + 32);                                 \
    BUF##2 = *(const bf16x8*)(wp_ + 64);                                 \
    BUF##3 = *(const bf16x8*)(wp_ + 96);                                 \
    B2V = b2[(IG) * 64 + ocol];                                          \
  } while (0)

#define STEP(BUF, B2V, IL) do {                                          \
    _Pragma("unroll")                                                    \
    for (int mt = 0; mt < 4; ++mt) {                                     \
      f32x4 P = {B2V, B2V, B2V, B2V};                                    \
      P = __builtin_amdgcn_mfma_f32_16x16x32_bf16(tf[mt][0], BUF##0, P, 0, 0, 0); \
      P = __builtin_amdgcn_mfma_f32_16x16x32_bf16(tf[mt][1], BUF##1, P, 0, 0, 0); \
      P = __builtin_amdgcn_mfma_f32_16x16x32_bf16(tf[mt][2], BUF##2, P, 0, 0, 0); \
      P = __builtin_amdgcn_mfma_f32_16x16x32_bf16(tf[mt][3], BUF##3, P, 0, 0, 0); \
      f32x4 hf = *(const f32x4*)(HsT + (IL) * HS_STRIDE + mt * 16 + lq * 4); \
      _Pragma("unroll")                                                  \
      for (int r = 0; r < 4; ++r) C[mt][r] = fmaf(hf[r], P[r], C[mt][r]); \
    }                                                                    \
  } while (0)

  LDW2(ba, b2a, ig0 + 0);
  LDW2(bb, b2b, ig0 + 1);
  LDW2(bc, b2c, ig0 + 2);

  __syncthreads();  // HsT ready

  f32x4 C[4] = {};
#pragma unroll 1
  for (int il = 0; il < 32; il += 4) {
    int ig = ig0 + il;
    int p;
    p = (il + 3 < 32) ? ig + 3 : ig0 + 31;  LDW2(bd, b2d, p);
    STEP(ba, b2a, il + 0);
    p = (il + 4 < 32) ? ig + 4 : ig0 + 31;  LDW2(ba, b2a, p);
    STEP(bb, b2b, il + 1);
    p = (il + 5 < 32) ? ig + 5 : ig0 + 31;  LDW2(bb, b2b, p);
    STEP(bc, b2c, il + 2);
    p = (il + 6 < 32) ? ig + 6 : ig0 + 31;  LDW2(bc, b2c, p);
    STEP(bd, b2d, il + 3);
  }
#undef LDW2
#undef STEP

  // scatter-add partial sums to neigh[dst]
#pragma unroll
  for (int mt = 0; mt < 4; ++mt) {
#pragma unroll
    for (int r = 0; r < 4; ++r) {
      int el = mt * 16 + lq * 4 + r;
      atomicAdd(neigh + (size_t)Ds[el] * D + ocol, C[mt][r]);
    }
  }
}

// ------- GRU: x=relu(neigh+cb); gates via split-bf16 MFMA; h in place; re-zeroes neigh -------
__global__ __launch_bounds__(256) void k_gru(float* __restrict__ neigh,
                                             float* __restrict__ h,
                                             const __hip_bfloat16* __restrict__ Bhi,
                                             const __hip_bfloat16* __restrict__ Blo,
                                             const float* __restrict__ cb,
                                             const float* __restrict__ bih,
                                             const float* __restrict__ bhh) {
  __shared__ __hip_bfloat16 Ahi[32 * 128];
  __shared__ __hip_bfloat16 Alo[32 * 128];
  int tid = threadIdx.x;
  int n0 = blockIdx.x * 32;  // NV % 32 == 0
  for (int idx = tid; idx < 32 * 64; idx += 256) {
    int node = idx >> 6, f = idx & 63;
    int gn = n0 + node;
    float xv = fmaxf(neigh[(size_t)gn * D + f] + cb[f], 0.f);
    neigh[(size_t)gn * D + f] = 0.f;  // ready for next step's atomics
    float hv = h[(size_t)gn * D + f];
    __hip_bfloat16 xh = __float2bfloat16(xv);
    __hip_bfloat16 hh = __float2bfloat16(hv);
    Ahi[node * 128 + f] = xh;
    Ahi[node * 128 + 64 + f] = hh;
    Alo[node * 128 + f] = __float2bfloat16(xv - __bfloat162float(xh));
    Alo[node * 128 + 64 + f] = __float2bfloat16(hv - __bfloat162float(hh));
  }
  __syncthreads();
  int wave = tid >> 6, lane = tid & 63;
  int lr = lane & 15, lq = lane >> 4;
  f32x4 acc[2][4] = {};  // [m-tile][gate-class]
#pragma unroll
  for (int ks = 0; ks < 4; ++ks) {
    int koff = ks * 32 + lq * 8;
    bf16x8 ah[2], al[2], bh[4], bl[4];
#pragma unroll
    for (int mt = 0; mt < 2; ++mt) {
      ah[mt] = *(const bf16x8*)(Ahi + (mt * 16 + lr) * 128 + koff);
      al[mt] = *(const bf16x8*)(Alo + (mt * 16 + lr) * 128 + koff);
    }
#pragma unroll
    for (int cls = 0; cls < 4; ++cls) {
      int n = cls * 64 + wave * 16 + lr;
      bh[cls] = *(const bf16x8*)(Bhi + (size_t)n * 128 + koff);
      bl[cls] = *(const bf16x8*)(Blo + (size_t)n * 128 + koff);
    }
#pragma unroll
    for (int mt = 0; mt < 2; ++mt)
#pragma unroll
      for (int cls = 0; cls < 4; ++cls) {
        acc[mt][cls] = __builtin_amdgcn_mfma_f32_16x16x32_bf16(ah[mt], bh[cls], acc[mt][cls], 0, 0, 0);
        acc[mt][cls] = __builtin_amdgcn_mfma_f32_16x16x32_bf16(al[mt], bh[cls], acc[mt][cls], 0, 0, 0);
        acc[mt][cls] = __builtin_amdgcn_mfma_f32_16x16x32_bf16(ah[mt], bl[cls], acc[mt][cls], 0, 0, 0);
      }
  }
  int o = wave * 16 + lr;
  float b_r = bih[o] + bhh[o];
  float b_z = bih[64 + o] + bhh[64 + o];
  float b_in = bih[128 + o];
  float b_hn = bhh[128 + o];
#pragma unroll
  for (int mt = 0; mt < 2; ++mt) {
#pragma unroll
    for (int r = 0; r < 4; ++r) {
      int gn = n0 + mt * 16 + lq * 4 + r;
      float rs = acc[mt][0][r] + b_r;
      float zs = acc[mt][1][r] + b_z;
      float inn = acc[mt][2][r] + b_in;
      float hnn = acc[mt][3][r] + b_hn;
      float rg = 1.f / (1.f + __expf(-rs));
      float zg = 1.f / (1.f + __expf(-zs));
      float a = inn + rg * hnn;
      a = fminf(fmaxf(a, -15.f), 15.f);
      float e2 = __expf(2.f * a);
      float nn = (e2 - 1.f) / (e2 + 1.f);
      float hold = h[(size_t)gn * D + o];
      h[(size_t)gn * D + o] = (1.f - zg) * nn + zg * hold;
    }
  }
}

// ---------------- predictor: score_e = [h_src | h_dst] . pW + pb ----------------
__global__ __launch_bounds__(256) void k_pred(const float* __restrict__ h,
                                              const int* __restrict__ src,
                                              const int* __restrict__ dst,
                                              const float* __restrict__ pW,
                                              const float* __restrict__ pb,
                                              float* __restrict__ out) {
  int wave = threadIdx.x >> 6, lane = threadIdx.x & 63;
  int e = blockIdx.x * 4 + wave;
  int s = src[e], d2 = dst[e];
  float v = h[(size_t)s * D + lane] * pW[lane] + h[(size_t)d2 * D + lane] * pW[64 + lane];
#pragma unroll
  for (int off = 32; off >= 1; off >>= 1) v += __shfl_xor(v, off, 64);
  if (lane == 0) out[e] = v + pb[0];
}

extern "C" void kernel_launch(void* const* d_in, const int* in_sizes, int n_in,
                              void* d_out, int out_size, void* d_ws, size_t ws_size,
                              hipStream_t stream) {
  const float* node_feats = (const float*)d_in[0];
  const float* edge_feats = (const float*)d_in[1];
  const int* src = (const int*)d_in[2];
  const int* dst = (const int*)d_in[3];
  const float* proj_W = (const float*)d_in[4];
  const float* proj_b = (const float*)d_in[5];
  const float* en_W1 = (const float*)d_in[6];
  const float* en_b1 = (const float*)d_in[7];
  const float* en_W2 = (const float*)d_in[8];
  const float* en_b2 = (const float*)d_in[9];
  const float* conv_b = (const float*)d_in[10];
  const float* gru_Wih = (const float*)d_in[11];
  const float* gru_Whh = (const float*)d_in[12];
  const float* gru_bih = (const float*)d_in[13];
  const float* gru_bhh = (const float*)d_in[14];
  const float* pred_W = (const float*)d_in[15];
  const float* pred_b = (const float*)d_in[16];

  char* ws = (char*)d_ws;
  size_t off = 0;
  auto walloc = [&](size_t bytes) -> void* {
    void* p = ws + off;
    off = (off + bytes + 255) & ~(size_t)255;
    return p;
  };
  // total workspace: ~22 MB
  float* h = (float*)walloc((size_t)NV * D * 4);
  float* neigh = (float*)walloc((size_t)NV * D * 4);
  __hip_bfloat16* t_bf = (__hip_bfloat16*)walloc((size_t)NE * EHID * 2);
  __hip_bfloat16* w2_bf = (__hip_bfloat16*)walloc((size_t)D * D * EHID * 2);
  __hip_bfloat16* Bhi = (__hip_bfloat16*)walloc((size_t)256 * 128 * 2);
  __hip_bfloat16* Blo = (__hip_bfloat16*)walloc((size_t)256 * 128 * 2);

  k_proj<<<NV / 4, 256, 0, stream>>>(node_feats, proj_W, proj_b, h, neigh);
  k_edge1<<<NE / 2, 256, 0, stream>>>(edge_feats, en_W1, en_b1, t_bf);
  k_cvt_w2<<<(D * D * EHID + 255) / 256, 256, 0, stream>>>(en_W2, w2_bf);
  k_build_b<<<128, 256, 0, stream>>>(gru_Wih, gru_Whh, Bhi, Blo);
  for (int s = 0; s < NSTEPS; ++s) {
    k_msg<<<(NE / 64) * 2, 256, 0, stream>>>(h, t_bf, w2_bf, en_b2, src, dst, neigh);
    k_gru<<<NV / 32, 256, 0, stream>>>(neigh, h, Bhi, Blo, conv_b, gru_bih, gru_bhh);
  }
  k_pred<<<NE / 4, 256, 0, stream>>>(h, src, dst, pred_W, pred_b, (float*)d_out);
}

// Round 6
// 818.931 us; speedup vs baseline: 1.0873x; 1.0873x over previous
//
#include <hip/hip_runtime.h>
#include <hip/hip_bf16.h>
#include <cstdint>

#define NV 20000
#define NE 40000
#define NODE_IN 74
#define EDGE_IN 12
#define D 64
#define EHID 128
#define NSTEPS 6

typedef __bf16 bf16x8 __attribute__((ext_vector_type(8)));
typedef float f32x4 __attribute__((ext_vector_type(4)));

// ---------------- node projection: h = relu(nf @ Wp^T + bp); also zero neigh ----------------
__global__ __launch_bounds__(256) void k_proj(const float* __restrict__ nf,
                                              const float* __restrict__ W,
                                              const float* __restrict__ b,
                                              float* __restrict__ h,
                                              float* __restrict__ neigh) {
  __shared__ float sn[4][NODE_IN];
  int tid = threadIdx.x;
  int nb = blockIdx.x * 4;
  for (int idx = tid; idx < 4 * NODE_IN; idx += 256) {
    int r = idx / NODE_IN, c = idx % NODE_IN;
    sn[r][c] = nf[(size_t)(nb + r) * NODE_IN + c];
  }
  __syncthreads();
  int nl = tid >> 6, o = tid & 63;
  float acc = b[o];
#pragma unroll
  for (int i = 0; i < NODE_IN; ++i) acc = fmaf(sn[nl][i], W[o * NODE_IN + i], acc);
  h[(size_t)(nb + nl) * D + o] = fmaxf(acc, 0.f);
  neigh[(size_t)(nb + nl) * D + o] = 0.f;
}

// ------------- edge net layer 1: t = relu(ef @ W1^T + b1), bf16 -------------
__global__ __launch_bounds__(256) void k_edge1(const float* __restrict__ ef,
                                               const float* __restrict__ W1,
                                               const float* __restrict__ b1,
                                               __hip_bfloat16* __restrict__ t_bf) {
  __shared__ float se[2][EDGE_IN];
  int tid = threadIdx.x;
  int eb = blockIdx.x * 2;
  if (tid < 2 * EDGE_IN)
    se[tid / EDGE_IN][tid % EDGE_IN] =
        ef[(size_t)(eb + tid / EDGE_IN) * EDGE_IN + tid % EDGE_IN];
  __syncthreads();
  int el = tid >> 7, k = tid & 127;
  float acc = b1[k];
#pragma unroll
  for (int j = 0; j < EDGE_IN; ++j) acc = fmaf(se[el][j], W1[k * EDGE_IN + j], acc);
  t_bf[(size_t)(eb + el) * EHID + k] = __float2bfloat16(fmaxf(acc, 0.f));
}

// ---------------- W2 fp32 -> bf16 ----------------
__global__ __launch_bounds__(256) void k_cvt_w2(const float* __restrict__ W2,
                                                __hip_bfloat16* __restrict__ w2b) {
  int idx = blockIdx.x * 256 + threadIdx.x;
  if (idx < D * D * EHID) w2b[idx] = __float2bfloat16(W2[idx]);
}

// ------- build GRU B matrix (256 x 128), hi/lo bf16 split -------
__global__ __launch_bounds__(256) void k_build_b(const float* __restrict__ Wih,
                                                 const float* __restrict__ Whh,
                                                 __hip_bfloat16* __restrict__ Bhi,
                                                 __hip_bfloat16* __restrict__ Blo) {
  int idx = blockIdx.x * 256 + threadIdx.x;  // 32768 total
  int n = idx >> 7, k = idx & 127;
  int o = n & 63, cls = n >> 6;
  float v;
  if (cls == 0)      v = (k < 64) ? Wih[o * 64 + k]         : Whh[o * 64 + (k - 64)];
  else if (cls == 1) v = (k < 64) ? Wih[(64 + o) * 64 + k]  : Whh[(64 + o) * 64 + (k - 64)];
  else if (cls == 2) v = (k < 64) ? Wih[(128 + o) * 64 + k] : 0.f;
  else               v = (k < 64) ? 0.f                     : Whh[(128 + o) * 64 + (k - 64)];
  __hip_bfloat16 hi = __float2bfloat16(v);
  Bhi[idx] = hi;
  Blo[idx] = __float2bfloat16(v - __bfloat162float(hi));
}

// ------- fused NNConv message+aggregate, W2 shared via LDS -------
// Block: 128 edges, 512 threads (8 waves). Wave w: edge-half wm=w&1 (64 edges),
// col-group wg=w>>1 (16 cols). Per i: W2_i (64x128 bf16, 16 KB) staged into LDS
// double-buffer by all 512 threads (plain load + ds_write_b128; stride 136 breaks
// bank conflicts), then each wave ds_reads its B-frags. t-frags register-resident.
// i-start rotated per block to decorrelate L2 traffic.
#define WB_STRIDE 136   // bf16 elems per row (128 + 8 pad)
#define HS2_STRIDE 132  // f32 elems per row (128 + 4 pad)
__global__ __launch_bounds__(512, 3) void k_msg(const float* __restrict__ h,
                                                const __hip_bfloat16* __restrict__ t_bf,
                                                const __hip_bfloat16* __restrict__ w2,
                                                const float* __restrict__ b2,
                                                const int* __restrict__ src,
                                                const int* __restrict__ dst,
                                                float* __restrict__ neigh) {
  __shared__ __align__(16) __hip_bfloat16 Wb2[2 * 64 * WB_STRIDE];  // 34 KB
  __shared__ __align__(16) float HsT[64 * HS2_STRIDE];              // [i][edge] 33.8 KB
  __shared__ int Ss[128];
  __shared__ int Ds[128];
  int tid = threadIdx.x;
  int e0 = blockIdx.x * 128;
  int rot = blockIdx.x & 63;

  if (tid < 128) {
    int e = e0 + tid; if (e > NE - 1) e = NE - 1;
    Ss[tid] = src[e];
    Ds[tid] = dst[e];
  }
  __syncthreads();  // Ss ready for gather
  // gather h[src] -> HsT[i][r] (all 64 i); lanes sweep i (coalesced 256B rows)
  for (int idx = tid; idx < 128 * 64; idx += 512) {
    int r = idx >> 6, i = idx & 63;
    HsT[i * HS2_STRIDE + r] = h[(size_t)Ss[r] * D + i];
  }

  int wave = tid >> 6, lane = tid & 63;
  int wm = wave & 1, wg = wave >> 1;
  int lr = lane & 15, lq = lane >> 4;
  const int ocol = wg * 16 + lr;

  // loop-invariant A-frags: t rows for this wave's 4 M-tiles (64 edges) x 4 k-steps
  bf16x8 tf[4][4];
#pragma unroll
  for (int mt = 0; mt < 4; ++mt) {
    int er = e0 + wm * 64 + mt * 16 + lr; if (er > NE - 1) er = NE - 1;
#pragma unroll
    for (int ks = 0; ks < 4; ++ks)
      tf[mt][ks] = *(const bf16x8*)(t_bf + (size_t)er * EHID + ks * 32 + lq * 8);
  }

  // staging indices: thread handles 16B chunks c0=tid, c1=tid+512 of the 1024-chunk W2_i
  int c0 = tid, c1 = tid + 512;
  int l0 = (c0 >> 4) * WB_STRIDE + (c0 & 15) * 8;  // LDS elem offsets
  int l1 = (c1 >> 4) * WB_STRIDE + (c1 & 15) * 8;

  // prologue: load W2_i0 into regs
  int i_act = rot;
  uint4 pa = *(const uint4*)(w2 + (size_t)i_act * 8192 + c0 * 8);
  uint4 pb = *(const uint4*)(w2 + (size_t)i_act * 8192 + c1 * 8);
  float b2cur = b2[i_act * 64 + ocol];
  float b2nxt = 0.f;

  f32x4 C[4] = {};
#pragma unroll 1
  for (int il = 0; il < 64; ++il) {
    i_act = (il + rot) & 63;
    __hip_bfloat16* Wb = Wb2 + (il & 1) * (64 * WB_STRIDE);
    // commit staged regs to LDS buffer
    *(uint4*)(Wb + l0) = pa;
    *(uint4*)(Wb + l1) = pb;
    __syncthreads();  // buffer ready (also covers HsT gather on il==0)
    // prefetch W2 for il+1 (lands during compute)
    if (il < 63) {
      int inx = (il + 1 + rot) & 63;
      pa = *(const uint4*)(w2 + (size_t)inx * 8192 + c0 * 8);
      pb = *(const uint4*)(w2 + (size_t)inx * 8192 + c1 * 8);
      b2nxt = b2[inx * 64 + ocol];
    }
    // B-frags for this wave's 16 cols
    bf16x8 f0 = *(const bf16x8*)(Wb + (wg * 16 + lr) * WB_STRIDE + 0 * 32 + lq * 8);
    bf16x8 f1 = *(const bf16x8*)(Wb + (wg * 16 + lr) * WB_STRIDE + 1 * 32 + lq * 8);
    bf16x8 f2 = *(const bf16x8*)(Wb + (wg * 16 + lr) * WB_STRIDE + 2 * 32 + lq * 8);
    bf16x8 f3 = *(const bf16x8*)(Wb + (wg * 16 + lr) * WB_STRIDE + 3 * 32 + lq * 8);
#pragma unroll
    for (int mt = 0; mt < 4; ++mt) {
      f32x4 P = {b2cur, b2cur, b2cur, b2cur};
      P = __builtin_amdgcn_mfma_f32_16x16x32_bf16(tf[mt][0], f0, P, 0, 0, 0);
      P = __builtin_amdgcn_mfma_f32_16x16x32_bf16(tf[mt][1], f1, P, 0, 0, 0);
      P = __builtin_amdgcn_mfma_f32_16x16x32_bf16(tf[mt][2], f2, P, 0, 0, 0);
      P = __builtin_amdgcn_mfma_f32_16x16x32_bf16(tf[mt][3], f3, P, 0, 0, 0);
      f32x4 hf = *(const f32x4*)(HsT + i_act * HS2_STRIDE + wm * 64 + mt * 16 + lq * 4);
#pragma unroll
      for (int r = 0; r < 4; ++r) C[mt][r] = fmaf(hf[r], P[r], C[mt][r]);
    }
    b2cur = b2nxt;
    __syncthreads();  // all reads of this buffer done before il+2 overwrites it
  }

  // scatter-add to neigh[dst]
#pragma unroll
  for (int mt = 0; mt < 4; ++mt) {
#pragma unroll
    for (int r = 0; r < 4; ++r) {
      int el = wm * 64 + mt * 16 + lq * 4 + r;
      if (e0 + el < NE)
        atomicAdd(neigh + (size_t)Ds[el] * D + ocol, C[mt][r]);
    }
  }
}

// ------- GRU: x=relu(neigh+cb); gates via split-bf16 MFMA; h in place; re-zeroes neigh -------
__global__ __launch_bounds__(256) void k_gru(float* __restrict__ neigh,
                                             float* __restrict__ h,
                                             const __hip_bfloat16* __restrict__ Bhi,
                                             const __hip_bfloat16* __restrict__ Blo,
                                             const float* __restrict__ cb,
                                             const float* __restrict__ bih,
                                             const float* __restrict__ bhh) {
  __shared__ __hip_bfloat16 Ahi[32 * 128];
  __shared__ __hip_bfloat16 Alo[32 * 128];
  int tid = threadIdx.x;
  int n0 = blockIdx.x * 32;  // NV % 32 == 0
  for (int idx = tid; idx < 32 * 64; idx += 256) {
    int node = idx >> 6, f = idx & 63;
    int gn = n0 + node;
    float xv = fmaxf(neigh[(size_t)gn * D + f] + cb[f], 0.f);
    neigh[(size_t)gn * D + f] = 0.f;  // ready for next step's atomics
    float hv = h[(size_t)gn * D + f];
    __hip_bfloat16 xh = __float2bfloat16(xv);
    __hip_bfloat16 hh = __float2bfloat16(hv);
    Ahi[node * 128 + f] = xh;
    Ahi[node * 128 + 64 + f] = hh;
    Alo[node * 128 + f] = __float2bfloat16(xv - __bfloat162float(xh));
    Alo[node * 128 + 64 + f] = __float2bfloat16(hv - __bfloat162float(hh));
  }
  __syncthreads();
  int wave = tid >> 6, lane = tid & 63;
  int lr = lane & 15, lq = lane >> 4;
  f32x4 acc[2][4] = {};  // [m-tile][gate-class]
#pragma unroll
  for (int ks = 0; ks < 4; ++ks) {
    int koff = ks * 32 + lq * 8;
    bf16x8 ah[2], al[2], bh[4], bl[4];
#pragma unroll
    for (int mt = 0; mt < 2; ++mt) {
      ah[mt] = *(const bf16x8*)(Ahi + (mt * 16 + lr) * 128 + koff);
      al[mt] = *(const bf16x8*)(Alo + (mt * 16 + lr) * 128 + koff);
    }
#pragma unroll
    for (int cls = 0; cls < 4; ++cls) {
      int n = cls * 64 + wave * 16 + lr;
      bh[cls] = *(const bf16x8*)(Bhi + (size_t)n * 128 + koff);
      bl[cls] = *(const bf16x8*)(Blo + (size_t)n * 128 + koff);
    }
#pragma unroll
    for (int mt = 0; mt < 2; ++mt)
#pragma unroll
      for (int cls = 0; cls < 4; ++cls) {
        acc[mt][cls] = __builtin_amdgcn_mfma_f32_16x16x32_bf16(ah[mt], bh[cls], acc[mt][cls], 0, 0, 0);
        acc[mt][cls] = __builtin_amdgcn_mfma_f32_16x16x32_bf16(al[mt], bh[cls], acc[mt][cls], 0, 0, 0);
        acc[mt][cls] = __builtin_amdgcn_mfma_f32_16x16x32_bf16(ah[mt], bl[cls], acc[mt][cls], 0, 0, 0);
      }
  }
  int o = wave * 16 + lr;
  float b_r = bih[o] + bhh[o];
  float b_z = bih[64 + o] + bhh[64 + o];
  float b_in = bih[128 + o];
  float b_hn = bhh[128 + o];
#pragma unroll
  for (int mt = 0; mt < 2; ++mt) {
#pragma unroll
    for (int r = 0; r < 4; ++r) {
      int gn = n0 + mt * 16 + lq * 4 + r;
      float rs = acc[mt][0][r] + b_r;
      float zs = acc[mt][1][r] + b_z;
      float inn = acc[mt][2][r] + b_in;
      float hnn = acc[mt][3][r] + b_hn;
      float rg = 1.f / (1.f + __expf(-rs));
      float zg = 1.f / (1.f + __expf(-zs));
      float a = inn + rg * hnn;
      a = fminf(fmaxf(a, -15.f), 15.f);
      float e2 = __expf(2.f * a);
      float nn = (e2 - 1.f) / (e2 + 1.f);
      float hold = h[(size_t)gn * D + o];
      h[(size_t)gn * D + o] = (1.f - zg) * nn + zg * hold;
    }
  }
}

// ---------------- predictor: score_e = [h_src | h_dst] . pW + pb ----------------
__global__ __launch_bounds__(256) void k_pred(const float* __restrict__ h,
                                              const int* __restrict__ src,
                                              const int* __restrict__ dst,
                                              const float* __restrict__ pW,
                                              const float* __restrict__ pb,
                                              float* __restrict__ out) {
  int wave = threadIdx.x >> 6, lane = threadIdx.x & 63;
  int e = blockIdx.x * 4 + wave;
  int s = src[e], d2 = dst[e];
  float v = h[(size_t)s * D + lane] * pW[lane] + h[(size_t)d2 * D + lane] * pW[64 + lane];
#pragma unroll
  for (int off = 32; off >= 1; off >>= 1) v += __shfl_xor(v, off, 64);
  if (lane == 0) out[e] = v + pb[0];
}

extern "C" void kernel_launch(void* const* d_in, const int* in_sizes, int n_in,
                              void* d_out, int out_size, void* d_ws, size_t ws_size,
                              hipStream_t stream) {
  const float* node_feats = (const float*)d_in[0];
  const float* edge_feats = (const float*)d_in[1];
  const int* src = (const int*)d_in[2];
  const int* dst = (const int*)d_in[3];
  const float* proj_W = (const float*)d_in[4];
  const float* proj_b = (const float*)d_in[5];
  const float* en_W1 = (const float*)d_in[6];
  const float* en_b1 = (const float*)d_in[7];
  const float* en_W2 = (const float*)d_in[8];
  const float* en_b2 = (const float*)d_in[9];
  const float* conv_b = (const float*)d_in[10];
  const float* gru_Wih = (const float*)d_in[11];
  const float* gru_Whh = (const float*)d_in[12];
  const float* gru_bih = (const float*)d_in[13];
  const float* gru_bhh = (const float*)d_in[14];
  const float* pred_W = (const float*)d_in[15];
  const float* pred_b = (const float*)d_in[16];

  char* ws = (char*)d_ws;
  size_t off = 0;
  auto walloc = [&](size_t bytes) -> void* {
    void* p = ws + off;
    off = (off + bytes + 255) & ~(size_t)255;
    return p;
  };
  // total workspace: ~22 MB
  float* h = (float*)walloc((size_t)NV * D * 4);
  float* neigh = (float*)walloc((size_t)NV * D * 4);
  __hip_bfloat16* t_bf = (__hip_bfloat16*)walloc((size_t)NE * EHID * 2);
  __hip_bfloat16* w2_bf = (__hip_bfloat16*)walloc((size_t)D * D * EHID * 2);
  __hip_bfloat16* Bhi = (__hip_bfloat16*)walloc((size_t)256 * 128 * 2);
  __hip_bfloat16* Blo = (__hip_bfloat16*)walloc((size_t)256 * 128 * 2);

  k_proj<<<NV / 4, 256, 0, stream>>>(node_feats, proj_W, proj_b, h, neigh);
  k_edge1<<<NE / 2, 256, 0, stream>>>(edge_feats, en_W1, en_b1, t_bf);
  k_cvt_w2<<<(D * D * EHID + 255) / 256, 256, 0, stream>>>(en_W2, w2_bf);
  k_build_b<<<128, 256, 0, stream>>>(gru_Wih, gru_Whh, Bhi, Blo);
  for (int s = 0; s < NSTEPS; ++s) {
    k_msg<<<(NE + 127) / 128, 512, 0, stream>>>(h, t_bf, w2_bf, en_b2, src, dst, neigh);
    k_gru<<<NV / 32, 256, 0, stream>>>(neigh, h, Bhi, Blo, conv_b, gru_bih, gru_bhh);
  }
  k_pred<<<NE / 4, 256, 0, stream>>>(h, src, dst, pred_W, pred_b, (float*)d_out);
}